// Round 6
// baseline (211.967 us; speedup 1.0000x reference)
//
#include <hip/hip_runtime.h>
#include <hip/hip_bf16.h>

// AtomPoolingLayer: M=512, N=128 atoms, F=512, HID=128. fp32 in, fp32 out.
// out[m,f] = sum_n sigmoid(relu(h[m,n,:]@W1+b1)@W2+b2) * h[m,n,f]
//
// R12: R11 (206.7us, session best) proved the LDS-unit diagnosis; remaining
// slack is occupancy: 144.6KiB LDS -> 1 block/CU -> each CU runs 2 fully
// serial block-chains (A-load latency, MFMA, LDS phase never overlap).
// R12 = R11's lean structure at half block size: 64 atoms/block, 256 thr,
// As 64KiB + red 8KiB -> 72.3KiB -> 2 blocks/CU; neighbor block's HBM
// stream hides under this block's compute. Partial outputs + reduce_out
// (R6-verified) return. All numerics verbatim from R11/R6.

typedef unsigned short u16;
typedef unsigned int u32;
typedef __bf16 bf16x8 __attribute__((ext_vector_type(8)));
typedef float f32x4 __attribute__((ext_vector_type(4)));
typedef float f32x2 __attribute__((ext_vector_type(2)));
typedef u32 u32x4 __attribute__((ext_vector_type(4)));

#define M_MOL 512
#define N_ATOM 128
#define F_DIM 512
#define HID_DIM 128
#define ABLK 64
#define NBLK (M_MOL * 2)

static __device__ __forceinline__ u16 f2bf(float x) {
  u32 u = __float_as_uint(x);
  u32 r = (u + 0x7fffu + ((u >> 16) & 1u)) >> 16;  // RNE
  return (u16)r;
}
// repack two fp32x4 -> bf16x8 by truncation (|rel err| <= 2^-8)
static __device__ __forceinline__ bf16x8 pack8(u32x4 a, u32x4 b) {
  u32x4 r;
  r[0] = (a[0] >> 16) | (a[1] & 0xffff0000u);
  r[1] = (a[2] >> 16) | (a[3] & 0xffff0000u);
  r[2] = (b[0] >> 16) | (b[1] & 0xffff0000u);
  r[3] = (b[2] >> 16) | (b[3] & 0xffff0000u);
  return __builtin_bit_cast(bf16x8, r);
}

// ---- Kernel 1: W1 fp32 [F=512][HID=128] -> W1Tt bf16 [ks][hid][32] ----
__global__ __launch_bounds__(256) void transpose_w1(const float* __restrict__ W1,
                                                    u16* __restrict__ W1Tt) {
  __shared__ float tile[64][65];
  const int k0 = blockIdx.x * 64;
  const int n0 = blockIdx.y * 64;
  const int t = threadIdx.x;
  #pragma unroll
  for (int i = 0; i < 16; ++i) {
    const int lin = i * 256 + t;
    const int lr = lin >> 6, lc = lin & 63;
    tile[lc][lr] = W1[(size_t)(k0 + lr) * HID_DIM + (n0 + lc)];
  }
  __syncthreads();
  #pragma unroll
  for (int i = 0; i < 16; ++i) {
    const int lin = i * 256 + t;
    const int wr = lin >> 6, wc = lin & 63;   // wr: hid idx, wc: k idx
    const int k = k0 + wc;
    W1Tt[(size_t)(k >> 5) * (HID_DIM * 32) + (size_t)(n0 + wr) * 32 + (k & 31)] =
        f2bf(tile[wr][wc]);
  }
}

// ---- Kernel 2: 64-atom partial pooling; 256 threads (4 waves x 16 rows) ----
__global__ __launch_bounds__(256, 2) void pool_part(
    const float* __restrict__ h, const u16* __restrict__ W1Tt,
    const float* __restrict__ b1, const float* __restrict__ W2,
    const float* __restrict__ b2, float* __restrict__ part) {
  // As: h bf16, 64 rows x 512; 16-B chunk c of row r at phys chunk
  // (c&~7)|((c^r)&7)  -> conflict-free phase-2 reads (R6-verified layout).
  __shared__ u16 As[ABLK * F_DIM];        // 64 KiB
  __shared__ float red[4][F_DIM];         // 8 KiB
  __shared__ float w_s[ABLK];             // 256 B

  const int blk = blockIdx.x;
  const int tid = threadIdx.x;
  const int wv = tid >> 6;                // wave 0..3 -> local rows wv*16..+15
  const int lane = tid & 63;
  const int quad = lane >> 4;
  const int cl = lane & 15;

  // ---- A loads: lane (cl,quad) owns local row, k = ks*32+quad*8..+7 ----
  const int lrow = wv * 16 + cl;
  const float* hr = h + ((size_t)blk * ABLK + lrow) * F_DIM;
  const u32x4* ap = (const u32x4*)hr + quad * 2;
  u32x4 a32[16][2];
  #pragma unroll
  for (int ks = 0; ks < 16; ++ks) {
    a32[ks][0] = ap[ks * 8];
    a32[ks][1] = ap[ks * 8 + 1];
  }

  // ---- B preload: tiles 0,1 (L1/L2-hot) ----
  const u16* bg = W1Tt + cl * 32 + quad * 8;
  u32x4 bf[3][8];                         // statically indexed under unroll
  #pragma unroll
  for (int p = 0; p < 2; ++p)
    #pragma unroll
    for (int t = 0; t < 8; ++t)
      bf[p][t] = *(const u32x4*)(bg + (size_t)p * (HID_DIM * 32) + t * 512);

  // ---- pack fp32->bf16 into ah + write-through to As ----
  bf16x8 ah[16];
  #pragma unroll
  for (int ks = 0; ks < 16; ++ks) {
    ah[ks] = pack8(a32[ks][0], a32[ks][1]);
    const int c = ks * 4 + quad;
    const int phys = (c & ~7) | ((c ^ cl) & 7);   // lrow&7 == cl&7
    *(bf16x8*)(As + lrow * F_DIM + phys * 8) = ah[ks];
  }

  // ---- Phase 1: T = h @ W1, MFMA 16x16x32 bf16; B 3-deep reg pipeline ----
  f32x4 acc[8];
  #pragma unroll
  for (int t = 0; t < 8; ++t) acc[t] = (f32x4){0.f, 0.f, 0.f, 0.f};

  #pragma unroll
  for (int ks = 0; ks < 16; ++ks) {
    if (ks < 14) {                        // prefetch tile ks+2
      #pragma unroll
      for (int t = 0; t < 8; ++t)
        bf[(ks + 2) % 3][t] =
            *(const u32x4*)(bg + (size_t)(ks + 2) * (HID_DIM * 32) + t * 512);
    }
    #pragma unroll
    for (int t = 0; t < 8; ++t)
      acc[t] = __builtin_amdgcn_mfma_f32_16x16x32_bf16(
          ah[ks], __builtin_bit_cast(bf16x8, bf[ks % 3][t]), acc[t], 0, 0, 0);
  }

  // ---- Epilogue: w[row] = sigmoid(relu(T+b1)@W2 + b2)  (verified) ----
  float psum[4] = {0.f, 0.f, 0.f, 0.f};
  #pragma unroll
  for (int t = 0; t < 8; ++t) {
    const int hid = t * 16 + cl;
    const float b1v = b1[hid];
    const float w2v = W2[hid];
    #pragma unroll
    for (int r = 0; r < 4; ++r) {
      float tv = fmaxf(acc[t][r] + b1v, 0.f);
      psum[r] = fmaf(tv, w2v, psum[r]);
    }
  }
  #pragma unroll
  for (int off = 1; off < 16; off <<= 1)
    #pragma unroll
    for (int r = 0; r < 4; ++r)
      psum[r] += __shfl_xor(psum[r], off, 64);
  if (cl == 0) {
    const float b2v = b2[0];
    #pragma unroll
    for (int r = 0; r < 4; ++r)
      w_s[wv * 16 + quad * 4 + r] = 1.f / (1.f + __expf(-(psum[r] + b2v)));
  }
  // wave-local fence: covers w_s write AND this wave's As write-through.
  asm volatile("s_waitcnt lgkmcnt(0)" ::: "memory");
  __builtin_amdgcn_sched_barrier(0);

  // ---- Phase 2: weighted sum over own 16 rows from As (R6-verified) ----
  float facc[8] = {0.f, 0.f, 0.f, 0.f, 0.f, 0.f, 0.f, 0.f};
  #pragma unroll 4
  for (int i = 0; i < 16; ++i) {
    const int r = wv * 16 + i;
    const float wn = w_s[r];
    const int phys = (lane & ~7) | ((lane ^ i) & 7);   // r&7 == i&7
    bf16x8 hv = *(const bf16x8*)(As + r * F_DIM + phys * 8);
    u32x4 uv = __builtin_bit_cast(u32x4, hv);
    #pragma unroll
    for (int j = 0; j < 4; ++j) {
      facc[2 * j]     = fmaf(wn, __uint_as_float(uv[j] << 16), facc[2 * j]);
      facc[2 * j + 1] = fmaf(wn, __uint_as_float(uv[j] & 0xffff0000u), facc[2 * j + 1]);
    }
  }

  // ---- Cross-wave f-reduction (the ONLY barrier) ----
  #pragma unroll
  for (int j = 0; j < 8; ++j) red[wv][lane * 8 + j] = facc[j];
  __syncthreads();

  {
    const int f = tid * 2;
    f32x2 o;
    o[0] = red[0][f] + red[1][f] + red[2][f] + red[3][f];
    o[1] = red[0][f + 1] + red[1][f + 1] + red[2][f + 1] + red[3][f + 1];
    *(f32x2*)(part + (size_t)blk * F_DIM + f) = o;
  }
}

// ---- Kernel 3: out[m] = part[2m] + part[2m+1] ----
__global__ __launch_bounds__(256) void reduce_out(const float* __restrict__ part,
                                                  float* __restrict__ out) {
  const int m = blockIdx.x;
  const int f = threadIdx.x * 2;
  f32x2 a = *(const f32x2*)(part + (size_t)(2 * m) * F_DIM + f);
  f32x2 b = *(const f32x2*)(part + (size_t)(2 * m + 1) * F_DIM + f);
  f32x2 o;
  o[0] = a[0] + b[0];
  o[1] = a[1] + b[1];
  *(f32x2*)(out + (size_t)m * F_DIM + f) = o;
}

extern "C" void kernel_launch(void* const* d_in, const int* in_sizes, int n_in,
                              void* d_out, int out_size, void* d_ws, size_t ws_size,
                              hipStream_t stream) {
  const float* h  = (const float*)d_in[0];   // [512,128,512] fp32
  const float* W1 = (const float*)d_in[1];   // [512,128] fp32
  const float* b1 = (const float*)d_in[2];   // [128] fp32
  const float* W2 = (const float*)d_in[3];   // [128,1] fp32
  const float* b2 = (const float*)d_in[4];   // [1] fp32
  float* out = (float*)d_out;                // [512,512] fp32

  u16* W1Tt = (u16*)d_ws;                                 // 128 KiB
  float* part = (float*)((char*)d_ws + (size_t)HID_DIM * F_DIM * sizeof(u16));  // 2 MiB

  transpose_w1<<<dim3(8, 2), 256, 0, stream>>>(W1, W1Tt);
  pool_part<<<NBLK, 256, 0, stream>>>(h, W1Tt, b1, W2, b2, part);
  reduce_out<<<M_MOL, 256, 0, stream>>>(part, out);
}